// Round 11
// baseline (174.051 us; speedup 1.0000x reference)
//
#include <hip/hip_runtime.h>
#include <hip/hip_bf16.h>

// Problem dims
#define B_    2
#define CIN   128
#define COUT  128
#define DD    16
#define HH    32
#define WW    32
// out strides: [b][co][d2][h2][w2]
#define OS_H2 64
#define OS_D2 (64*64)
#define OS_CO (32*64*64)
#define OS_B  (COUT*OS_CO)

// phase-pair bf16 arrays (r7-verified):
//   XE[j] = (e_{2j}, e_{2j+1}),  XO[j] = (e_{2j+1}, e_{2j+2})
#define PD_D   18
#define PD_H   34
#define RD     17                      // dwords per row
#define RDB    68                      // bytes per row
#define HWDW   (PD_H*RD)               // 578 dwords per d-plane
#define PLB    (HWDW*4)                // 2312 bytes per d-plane
#define CIW    (PD_D*HWDW)             // 10404 dwords per (b,ci)
#define CIB    (CIW*4)                 // 41616 bytes
#define ARRD   ((size_t)B_*CIN*CIW)
#define ARRB   (ARRD*4)                // 10,653,696 bytes
#define AFOLD_BYTES (8*32*8*64*16)     // 2 MiB

typedef __attribute__((ext_vector_type(8))) short        short8;
typedef __attribute__((ext_vector_type(4))) float        floatx4;
typedef __attribute__((ext_vector_type(4))) unsigned int uint4v;

static __device__ __forceinline__ unsigned short f2bf(float f) {
    union { __hip_bfloat16 h; unsigned short u; } cv;
    cv.h = __float2bfloat16(f);
    return cv.u;
}

// ---------------------------------------------------------------------------
// Kernel 1: fold weights -> per-parity 2x2x2 bf16 kernels, MFMA A order,
// k = ci*8 + tap (r7-verified).
// ---------------------------------------------------------------------------
__global__ __launch_bounds__(256) void fold_kernel(const float* __restrict__ Wk,
                                                   unsigned short* __restrict__ Afold) {
    const int t = blockIdx.x * 256 + threadIdx.x;
    const int p  = t >> 14;
    const int ks = (t >> 9) & 31;
    const int ct = (t >> 6) & 7;
    const int l  = t & 63;
    const int co = ct * 16 + (l & 15);
    const int ci = ks * 4 + (l >> 4);
    const int ed = (p >> 2) & 1, eh = (p >> 1) & 1, ew = p & 1;

    const float* w = Wk + (co * CIN + ci) * 27;
    float wv[27];
    #pragma unroll
    for (int i = 0; i < 27; ++i) wv[i] = w[i];

    short8 pk;
    #pragma unroll
    for (int tt = 0; tt < 8; ++tt) {
        const int td = (tt >> 2) & 1, th = (tt >> 1) & 1, tw = tt & 1;
        const int dlo = ed ? (td ? 2 : 0) : (td ? 1 : 0);
        const int dhi = ed ? (td ? 2 : 1) : (td ? 2 : 0);
        const int hlo = eh ? (th ? 2 : 0) : (th ? 1 : 0);
        const int hhi = eh ? (th ? 2 : 1) : (th ? 2 : 0);
        const int wlo = ew ? (tw ? 2 : 0) : (tw ? 1 : 0);
        const int whi = ew ? (tw ? 2 : 1) : (tw ? 2 : 0);
        float s = 0.f;
        for (int kd = dlo; kd <= dhi; ++kd)
            for (int kh = hlo; kh <= hhi; ++kh)
                for (int kw = wlo; kw <= whi; ++kw)
                    s += wv[kd * 9 + kh * 3 + kw];
        pk[tt] = (short)f2bf(s);
    }
    reinterpret_cast<short8*>(Afold)[t] = pk;
}

// ---------------------------------------------------------------------------
// Kernel 2: convert+pad x -> XE (borders pre-zeroed by memset). (r7)
// ---------------------------------------------------------------------------
__global__ __launch_bounds__(256) void pad_kernel(const float* __restrict__ x,
                                                  unsigned* __restrict__ xe) {
    const int idx = blockIdx.x * 256 + threadIdx.x;
    const int w2 = idx & 15;
    const int h  = (idx >> 4) & 31;
    const int d  = (idx >> 9) & 15;
    const int ci = (idx >> 13) & 127;
    const int b  = (idx >> 20) & 1;
    const float2 v = *reinterpret_cast<const float2*>(
        x + (size_t)((b * CIN + ci) * DD + d) * (HH * WW) + h * WW + w2 * 2);
    xe[(size_t)((b * CIN + ci) * PD_D + d + 1) * HWDW
       + (h + 1) * RD + (w2 + 1)] = (unsigned)f2bf(v.x) | ((unsigned)f2bf(v.y) << 16);
}

// ---------------------------------------------------------------------------
// Kernel 3: XO[t] = (XE[t]>>16) | (XE[t+1]<<16)   (r7-verified)
// ---------------------------------------------------------------------------
__global__ __launch_bounds__(256) void xo_kernel(const unsigned* __restrict__ xe,
                                                 unsigned* __restrict__ xo) {
    const size_t t = (size_t)blockIdx.x * 256 + threadIdx.x;
    const unsigned e0 = xe[t];
    const unsigned e1 = (t + 1 < ARRD) ? xe[t + 1] : 0u;
    xo[t] = (e0 >> 16) | (e1 << 16);
}

// ---------------------------------------------------------------------------
// Kernel 4: per-parity implicit GEMM — NO LDS, NO BARRIERS.
//   Each lane loads its MFMA B-fragment directly from XE/XO: fragment
//   (ksl,nt) = 4 dwords at lane-base + {0,RDB,PLB,PLB+RDB} (the 8 taps of
//   ci = kc*8 + ksl*4 + (lane>>4) at n = n0 + nt*16 + (lane&15)).
//   Ping-pong depth-1 prefetch; compiler emits exact per-register vmcnt.
// ---------------------------------------------------------------------------
__global__ __launch_bounds__(256, 2) void upconv_mfma(
    const char* __restrict__ xe_c, const char* __restrict__ xo_c,
    const unsigned short* __restrict__ Afold,
    const float* __restrict__ bias,
    float* __restrict__ out)
{
    const int tid  = threadIdx.x;
    const int wave = tid >> 6;
    const int lane = tid & 63;

    const int d      = blockIdx.x >> 3;
    const int h_base = (blockIdx.x & 7) * 4;
    const int p      = blockIdx.y;
    const int b      = blockIdx.z;
    const int ed = (p >> 2) & 1, eh = (p >> 1) & 1, ew = p & 1;

    const int co0 = (wave >> 1) * 64;
    const int n0  = (wave & 1) * 64;
    const int ct0 = (wave >> 1) * 4;

    // ---- per-lane B base (chunk 0, fragment (0,0)) ----
    // n = n0 + nt*16 + (lane&15); parity(n) = lane&1.
    // n even: arr = ew?XE:XO, col = s+ew ; n odd: arr = ew?XO:XE, col = s+1
    const int lodd = lane & 1;
    const char* arr = (ew != lodd) ? xe_c : xo_c;
    const int ci_l  = lane >> 4;                       // ci offset within k-block
    const int col0  = ((lane & 15) >> 1) + (lodd ? 1 : ew);
    const char* bbase = arr
        + ((long)(b * CIN + ci_l) * PD_D + (d + ed)) * (long)PLB
        + (long)(h_base + eh + (n0 >> 5)) * RDB
        + (long)col0 * 4;

    floatx4 acc[4][4];
    #pragma unroll
    for (int i = 0; i < 4; ++i)
        #pragma unroll
        for (int j = 0; j < 4; ++j)
            acc[i][j] = (floatx4){0.f, 0.f, 0.f, 0.f};

    const short8* Ap = reinterpret_cast<const short8*>(Afold);

    uint4v B0[2][4], B1[2][4];
    short8 A0[2][4], A1[2][4];

    // fragment (ksl,nt) offset: ksl*4*CIB (ci) + (nt>>1)*RDB (h) + (nt&1)*32 (w+16)
    #define LOADB(Bf, kc)                                                       \
        do {                                                                    \
            _Pragma("unroll")                                                   \
            for (int ksl = 0; ksl < 2; ++ksl)                                   \
                _Pragma("unroll")                                               \
                for (int nt = 0; nt < 4; ++nt) {                                \
                    const char* fb = bbase + (long)((kc) * 8 + ksl * 4) * CIB   \
                                   + (nt >> 1) * RDB + (nt & 1) * 32;           \
                    Bf[ksl][nt] = (uint4v){                                     \
                        *(const unsigned*)(fb),                                 \
                        *(const unsigned*)(fb + RDB),                           \
                        *(const unsigned*)(fb + PLB),                           \
                        *(const unsigned*)(fb + PLB + RDB)};                    \
                }                                                               \
        } while (0)

    #define LOADA(Af, kc)                                                       \
        do {                                                                    \
            _Pragma("unroll")                                                   \
            for (int ksl = 0; ksl < 2; ++ksl)                                   \
                _Pragma("unroll")                                               \
                for (int ct = 0; ct < 4; ++ct)                                  \
                    Af[ksl][ct] = Ap[(size_t)(((p) * 32 + (kc) * 2 + ksl) * 8   \
                                              + ct0 + ct) * 64 + lane];         \
        } while (0)

    #define MFMAC(Af, Bf)                                                       \
        do {                                                                    \
            __builtin_amdgcn_s_setprio(1);                                      \
            _Pragma("unroll")                                                   \
            for (int ksl = 0; ksl < 2; ++ksl)                                   \
                _Pragma("unroll")                                               \
                for (int nt = 0; nt < 4; ++nt) {                                \
                    const short8 bfr = __builtin_bit_cast(short8, Bf[ksl][nt]); \
                    _Pragma("unroll")                                           \
                    for (int ct = 0; ct < 4; ++ct)                              \
                        acc[ct][nt] = __builtin_amdgcn_mfma_f32_16x16x32_bf16(  \
                            Af[ksl][ct], bfr, acc[ct][nt], 0, 0, 0);            \
                }                                                               \
            __builtin_amdgcn_s_setprio(0);                                      \
        } while (0)

    LOADB(B0, 0);
    LOADA(A0, 0);
    for (int kc = 0; kc < 16; kc += 2) {
        LOADB(B1, kc + 1);
        LOADA(A1, kc + 1);
        MFMAC(A0, B0);
        if (kc + 2 < 16) {
            LOADB(B0, kc + 2);
            LOADA(A0, kc + 2);
        }
        MFMAC(A1, B1);
    }
    #undef MFMAC
    #undef LOADA
    #undef LOADB

    // ---- epilogue: add bias, scatter to upsampled layout (r7-verified) ----
    float* ob = out + (size_t)b * OS_B + (size_t)(2 * d + ed) * OS_D2;
    #pragma unroll
    for (int ct = 0; ct < 4; ++ct) {
        #pragma unroll
        for (int j = 0; j < 4; ++j) {
            const int co = co0 + ct * 16 + (lane >> 4) * 4 + j;
            const float bv = bias[co];
            #pragma unroll
            for (int nt = 0; nt < 4; ++nt) {
                const int n  = n0 + nt * 16 + (lane & 15);
                const int hh = n >> 5, wl = n & 31;
                const int h2 = 2 * (h_base + hh) + eh;
                const int w2 = 2 * wl + ew;
                ob[(size_t)co * OS_CO + h2 * OS_H2 + w2] = acc[ct][nt][j] + bv;
            }
        }
    }
}

extern "C" void kernel_launch(void* const* d_in, const int* in_sizes, int n_in,
                              void* d_out, int out_size, void* d_ws, size_t ws_size,
                              hipStream_t stream) {
    const float* x    = (const float*)d_in[0];
    const float* Wk   = (const float*)d_in[1];
    const float* bias = (const float*)d_in[2];
    float* out        = (float*)d_out;

    unsigned short* Afold = (unsigned short*)d_ws;
    char* xe = (char*)d_ws + AFOLD_BYTES;
    char* xo = xe + ARRB;

    hipMemsetAsync(xe, 0, ARRB, stream);
    pad_kernel<<<8192, 256, 0, stream>>>(x, (unsigned*)xe);
    xo_kernel<<<(unsigned)(ARRD / 256), 256, 0, stream>>>((const unsigned*)xe,
                                                          (unsigned*)xo);
    fold_kernel<<<512, 256, 0, stream>>>(Wk, Afold);

    dim3 grid(DD * 8, 8, B_);   // (128, 8 parity, 2 batch)
    upconv_mfma<<<grid, 256, 0, stream>>>(xe, xo, Afold, bias, out);
}